// Round 2
// baseline (552.727 us; speedup 1.0000x reference)
//
#include <hip/hip_runtime.h>
#include <math.h>

// Problem constants (reference: B,T,D = 128,2048,256; LAMDA=0.5)
#define BB 128
#define TT 2048
#define DD 256
#define SPLIT 8
#define ROWS_PER_BLOCK (TT / SPLIT)            // 256
#define WAVES 4
// Row-group decomposition: 16 lanes per row, 4 rows per wave per batch.
#define G 16
#define RPB 4                                  // rows per batch (64/G)
#define NB 16                                  // batches -> 64 rows per wave

// Workspace layout (in floats)
#define WS_MIDS 0                               // B*D
#define WS_P1ACC (WS_MIDS + BB * DD)            // B*SPLIT*D
#define WS_P1SUM (WS_P1ACC + BB * SPLIT * DD)   // B*SPLIT
#define WS_P2ACC_SS (WS_P1SUM + BB * SPLIT)     // B*SPLIT*D
#define WS_P2ACC_SA (WS_P2ACC_SS + BB * SPLIT * DD) // B*SPLIT*D
#define WS_P2SUM_SS (WS_P2ACC_SA + BB * SPLIT * DD) // B*SPLIT
#define WS_P2SUM_SA (WS_P2SUM_SS + BB * SPLIT)      // B*SPLIT

__device__ __forceinline__ float dot4(const float4& a, const float4& b) {
    return a.x * b.x + a.y * b.y + a.z * b.z + a.w * b.w;
}

// Overflow-safe tanh: tanh(x) = sign(x) * (1 - e^{-2|x|}) / (1 + e^{-2|x|})
__device__ __forceinline__ float tanh_fast(float x) {
    float ax = fabsf(x);
    float t = __expf(-2.0f * ax);
    float th = (1.0f - t) / (1.0f + t);
    return copysignf(th, x);
}

__device__ __forceinline__ float4 shfl_xor4(float4 v, int off) {
    float4 r;
    r.x = __shfl_xor(v.x, off, 64);
    r.y = __shfl_xor(v.y, off, 64);
    r.z = __shfl_xor(v.z, off, 64);
    r.w = __shfl_xor(v.w, off, 64);
    return r;
}

// K0: mids[b,i] = sum_j aspect[b,j] * W_mul[i,j]   (aspect @ W_mul.T)
__global__ __launch_bounds__(DD) void mids_kernel(
    const float* __restrict__ aspect, const float* __restrict__ W,
    float* __restrict__ ws)
{
    const int b = blockIdx.x;
    const int i = threadIdx.x;
    __shared__ float a[DD];
    a[i] = aspect[b * DD + i];
    __syncthreads();
    const float4* wrow = (const float4*)(W + (size_t)i * DD);
    float acc = 0.f;
    #pragma unroll 8
    for (int j4 = 0; j4 < DD / 4; ++j4) {
        float4 w4 = wrow[j4];
        acc += a[4 * j4 + 0] * w4.x + a[4 * j4 + 1] * w4.y +
               a[4 * j4 + 2] * w4.z + a[4 * j4 + 3] * w4.w;
    }
    ws[WS_MIDS + b * DD + i] = acc;
}

// K_main: grid (SPLIT, B, 2).  z=0: multiplicative pass over aspect_memory;
// z=1: two additive heads over sentiment_memory (query terms are
// softmax-shift-invariant -> omitted; partials are linear sums, no max
// subtraction needed since scores are bounded).
//
// Decomposition: 16 lanes per row (lane = g*16+c; group g owns one row,
// lane c owns cols {j*64 + c*4 .. +4} for j=0..3). Score reduce = 4-step
// butterfly inside the 16-lane group; result lands broadcast on exactly the
// lanes that weight that row. Loads double-buffered one batch ahead.
__global__ __launch_bounds__(256) void pass_kernel(
    const float* __restrict__ smem_g, const float* __restrict__ amem_g,
    const float* __restrict__ mask, const float* __restrict__ w_ss,
    const float* __restrict__ w_sa, const float* __restrict__ b_mul,
    float* __restrict__ ws)
{
    const int s = blockIdx.x;
    const int b = blockIdx.y;
    const int tid = threadIdx.x;
    const int wave = tid >> 6;
    const int lane = tid & 63;
    const int g = lane >> 4;        // row group 0..3
    const int c = lane & 15;        // column chunk 0..15
    const int t0 = s * ROWS_PER_BLOCK + wave * (RPB * NB);

    __shared__ __align__(16) float lds_acc[2 * WAVES * DD]; // 8 KB
    __shared__ float lds_sum[2 * WAVES];

    if (blockIdx.z == 0) {
        // ---- aspect pass: score = tanh(mem . mids + b_mul) ----
        float4 m4[4];
        #pragma unroll
        for (int j = 0; j < 4; ++j)
            m4[j] = *(const float4*)(ws + WS_MIDS + b * DD + j * 64 + c * 4);
        const float bm = b_mul[0];
        const float* base = amem_g + ((size_t)b * TT + t0 + g) * DD + c * 4;

        float4 cur[4], nxt[4];
        #pragma unroll
        for (int j = 0; j < 4; ++j)
            cur[j] = *(const float4*)(base + j * 64);

        float4 acc[4];
        #pragma unroll
        for (int j = 0; j < 4; ++j) acc[j] = make_float4(0.f, 0.f, 0.f, 0.f);
        float lsum = 0.f;

        #pragma unroll
        for (int i = 0; i < NB; ++i) {
            if (i + 1 < NB) {
                #pragma unroll
                for (int j = 0; j < 4; ++j)
                    nxt[j] = *(const float4*)(base + (size_t)(i + 1) * RPB * DD + j * 64);
            }
            float d = 0.f;
            #pragma unroll
            for (int j = 0; j < 4; ++j) d += dot4(cur[j], m4[j]);
            #pragma unroll
            for (int off = 1; off < G; off <<= 1)
                d += __shfl_xor(d, off, 64);
            float e = __expf(tanh_fast(d + bm));
            lsum += e;
            #pragma unroll
            for (int j = 0; j < 4; ++j) {
                acc[j].x += e * cur[j].x; acc[j].y += e * cur[j].y;
                acc[j].z += e * cur[j].z; acc[j].w += e * cur[j].w;
            }
            #pragma unroll
            for (int j = 0; j < 4; ++j) cur[j] = nxt[j];
        }
        // cross-group combine (once per wave)
        #pragma unroll
        for (int j = 0; j < 4; ++j) {
            float4 o = shfl_xor4(acc[j], 16);
            acc[j].x += o.x; acc[j].y += o.y; acc[j].z += o.z; acc[j].w += o.w;
            o = shfl_xor4(acc[j], 32);
            acc[j].x += o.x; acc[j].y += o.y; acc[j].z += o.z; acc[j].w += o.w;
        }
        lsum += __shfl_xor(lsum, 16, 64);
        lsum += __shfl_xor(lsum, 32, 64);
        if (g == 0) {
            #pragma unroll
            for (int j = 0; j < 4; ++j)
                *(float4*)(lds_acc + wave * DD + j * 64 + c * 4) = acc[j];
        }
        if (lane == 0) lds_sum[wave] = lsum;
        __syncthreads();
        float tot = lds_acc[0 * DD + tid] + lds_acc[1 * DD + tid] +
                    lds_acc[2 * DD + tid] + lds_acc[3 * DD + tid];
        ws[WS_P1ACC + (size_t)(b * SPLIT + s) * DD + tid] = tot;
        if (tid == 0)
            ws[WS_P1SUM + b * SPLIT + s] =
                lds_sum[0] + lds_sum[1] + lds_sum[2] + lds_sum[3];
    } else {
        // ---- sentiment pass: two additive heads share the memory read ----
        float4 wss4[4], wsa4[4];
        #pragma unroll
        for (int j = 0; j < 4; ++j) {
            wss4[j] = *(const float4*)(w_ss + j * 64 + c * 4);
            wsa4[j] = *(const float4*)(w_sa + j * 64 + c * 4);
        }
        const float* base = smem_g + ((size_t)b * TT + t0 + g) * DD + c * 4;
        const float* mrow = mask + (size_t)b * TT + t0;

        float4 cur[4], nxt[4];
        #pragma unroll
        for (int j = 0; j < 4; ++j)
            cur[j] = *(const float4*)(base + j * 64);

        float4 accss[4], accsa[4];
        #pragma unroll
        for (int j = 0; j < 4; ++j) {
            accss[j] = make_float4(0.f, 0.f, 0.f, 0.f);
            accsa[j] = make_float4(0.f, 0.f, 0.f, 0.f);
        }
        float lss = 0.f, lsa = 0.f;

        #pragma unroll
        for (int i = 0; i < NB; ++i) {
            if (i + 1 < NB) {
                #pragma unroll
                for (int j = 0; j < 4; ++j)
                    nxt[j] = *(const float4*)(base + (size_t)(i + 1) * RPB * DD + j * 64);
            }
            float dss = 0.f, dsa = 0.f;
            #pragma unroll
            for (int j = 0; j < 4; ++j) {
                dss += dot4(cur[j], wss4[j]);
                dsa += dot4(cur[j], wsa4[j]);
            }
            #pragma unroll
            for (int off = 1; off < G; off <<= 1) {
                dss += __shfl_xor(dss, off, 64);
                dsa += __shfl_xor(dsa, off, 64);
            }
            float m = mrow[i * RPB + g];
            float ess = __expf(dss) * m;
            float esa = __expf(dsa) * m;
            lss += ess;
            lsa += esa;
            #pragma unroll
            for (int j = 0; j < 4; ++j) {
                accss[j].x += ess * cur[j].x; accss[j].y += ess * cur[j].y;
                accss[j].z += ess * cur[j].z; accss[j].w += ess * cur[j].w;
                accsa[j].x += esa * cur[j].x; accsa[j].y += esa * cur[j].y;
                accsa[j].z += esa * cur[j].z; accsa[j].w += esa * cur[j].w;
            }
            #pragma unroll
            for (int j = 0; j < 4; ++j) cur[j] = nxt[j];
        }
        // cross-group combine (once per wave)
        #pragma unroll
        for (int j = 0; j < 4; ++j) {
            float4 o = shfl_xor4(accss[j], 16);
            accss[j].x += o.x; accss[j].y += o.y; accss[j].z += o.z; accss[j].w += o.w;
            o = shfl_xor4(accss[j], 32);
            accss[j].x += o.x; accss[j].y += o.y; accss[j].z += o.z; accss[j].w += o.w;
            o = shfl_xor4(accsa[j], 16);
            accsa[j].x += o.x; accsa[j].y += o.y; accsa[j].z += o.z; accsa[j].w += o.w;
            o = shfl_xor4(accsa[j], 32);
            accsa[j].x += o.x; accsa[j].y += o.y; accsa[j].z += o.z; accsa[j].w += o.w;
        }
        lss += __shfl_xor(lss, 16, 64);
        lss += __shfl_xor(lss, 32, 64);
        lsa += __shfl_xor(lsa, 16, 64);
        lsa += __shfl_xor(lsa, 32, 64);
        if (g == 0) {
            #pragma unroll
            for (int j = 0; j < 4; ++j) {
                *(float4*)(lds_acc + wave * DD + j * 64 + c * 4) = accss[j];
                *(float4*)(lds_acc + (WAVES + wave) * DD + j * 64 + c * 4) = accsa[j];
            }
        }
        if (lane == 0) {
            lds_sum[wave] = lss;
            lds_sum[WAVES + wave] = lsa;
        }
        __syncthreads();
        float tot_ss = lds_acc[0 * DD + tid] + lds_acc[1 * DD + tid] +
                       lds_acc[2 * DD + tid] + lds_acc[3 * DD + tid];
        float tot_sa = lds_acc[(WAVES + 0) * DD + tid] + lds_acc[(WAVES + 1) * DD + tid] +
                       lds_acc[(WAVES + 2) * DD + tid] + lds_acc[(WAVES + 3) * DD + tid];
        ws[WS_P2ACC_SS + (size_t)(b * SPLIT + s) * DD + tid] = tot_ss;
        ws[WS_P2ACC_SA + (size_t)(b * SPLIT + s) * DD + tid] = tot_sa;
        if (tid == 0) {
            ws[WS_P2SUM_SS + b * SPLIT + s] =
                lds_sum[0] + lds_sum[1] + lds_sum[2] + lds_sum[3];
            ws[WS_P2SUM_SA + b * SPLIT + s] =
                lds_sum[4] + lds_sum[5] + lds_sum[6] + lds_sum[7];
        }
    }
}

// K_combine: grid (B, 2).  y=0: aspect_out = aspect + new_aspect.
// y=1: sentiment_out = 0.5*acc_ss/l_ss + 0.5*acc_sa/l_sa.
__global__ __launch_bounds__(DD) void combine_kernel(
    const float* __restrict__ aspect, const float* __restrict__ ws,
    float* __restrict__ out)
{
    const int b = blockIdx.x;
    const int d = threadIdx.x;
    if (blockIdx.y == 0) {
        float acc = 0.f, l = 0.f;
        #pragma unroll
        for (int s = 0; s < SPLIT; ++s)
            acc += ws[WS_P1ACC + (size_t)(b * SPLIT + s) * DD + d];
        #pragma unroll
        for (int s = 0; s < SPLIT; ++s)
            l += ws[WS_P1SUM + b * SPLIT + s];
        out[BB * DD + b * DD + d] = aspect[b * DD + d] + acc / l;
    } else {
        float ass = 0.f, asa = 0.f, lss = 0.f, lsa = 0.f;
        #pragma unroll
        for (int s = 0; s < SPLIT; ++s) {
            ass += ws[WS_P2ACC_SS + (size_t)(b * SPLIT + s) * DD + d];
            asa += ws[WS_P2ACC_SA + (size_t)(b * SPLIT + s) * DD + d];
        }
        #pragma unroll
        for (int s = 0; s < SPLIT; ++s) {
            lss += ws[WS_P2SUM_SS + b * SPLIT + s];
            lsa += ws[WS_P2SUM_SA + b * SPLIT + s];
        }
        out[b * DD + d] = 0.5f * (ass / lss) + 0.5f * (asa / lsa);
    }
}

extern "C" void kernel_launch(void* const* d_in, const int* in_sizes, int n_in,
                              void* d_out, int out_size, void* d_ws, size_t ws_size,
                              hipStream_t stream) {
    (void)in_sizes; (void)n_in; (void)out_size; (void)ws_size;
    const float* aspect = (const float*)d_in[1];
    const float* smem   = (const float*)d_in[2];
    const float* amem   = (const float*)d_in[3];
    const float* mask   = (const float*)d_in[4];
    const float* W_mul  = (const float*)d_in[5];
    const float* b_mul  = (const float*)d_in[6];
    const float* w_ss   = (const float*)d_in[7];
    const float* w_sa   = (const float*)d_in[9];
    float* out = (float*)d_out;
    float* ws  = (float*)d_ws;

    mids_kernel<<<BB, DD, 0, stream>>>(aspect, W_mul, ws);
    pass_kernel<<<dim3(SPLIT, BB, 2), 256, 0, stream>>>(
        smem, amem, mask, w_ss, w_sa, b_mul, ws);
    combine_kernel<<<dim3(BB, 2), DD, 0, stream>>>(aspect, ws, out);
}